// Round 4
// baseline (158.115 us; speedup 1.0000x reference)
//
#include <hip/hip_runtime.h>

#define GAMMA 0.99f
#define LAM   0.95f

constexpr int CHUNK = 32;            // timesteps per thread; requires T == 64*CHUNK
constexpr int WPB   = 4;             // independent waves (rows) per block
constexpr int BLOCK = WPB * 64;

// One WAVE per row. Thread (lane) owns columns [lane*32, lane*32+32).
// Backward linear recurrence g[t] = delta[t] + c[t]*g[t+1] via affine
// composition: 32-deep per-thread compose -> 64-lane wave suffix scan ->
// per-thread replay. No __syncthreads, no LDS, no cross-wave traffic:
// waves are fully independent, each with its whole row's 24 dwordx4 loads
// issued before any consumption.
__global__ __launch_bounds__(BLOCK) void gae_wave_kernel(
    const float* __restrict__ rewards,
    const float* __restrict__ values,
    const float* __restrict__ next_value,
    const int*   __restrict__ done,
    float* __restrict__ adv_out,
    float* __restrict__ ret_out,
    int B, int T)
{
    const int wave = threadIdx.x >> 6;
    const int lane = threadIdx.x & 63;
    const int row  = blockIdx.x * WPB + wave;
    if (row >= B) return;                       // wave-uniform

    const long rowbase = (long)row * T;
    const int  col0    = lane * CHUNK;

    const float4* r4 = reinterpret_cast<const float4*>(rewards + rowbase + col0);
    const float4* v4 = reinterpret_cast<const float4*>(values  + rowbase + col0);
    const int4*   d4 = reinterpret_cast<const int4*>(done      + rowbase + col0);

    // ---- issue the whole row's loads up front (24 independent dwordx4) ----
    float4 ra[8], va[8];
    int4   da[8];
#pragma unroll
    for (int k = 0; k < 8; ++k) { ra[k] = r4[k]; }
#pragma unroll
    for (int k = 0; k < 8; ++k) { va[k] = v4[k]; }
#pragma unroll
    for (int k = 0; k < 8; ++k) { da[k] = d4[k]; }
    const float vboot = next_value[row];        // wave-uniform -> scalar load

    // ---- flatten ----
    float v[CHUNK], r[CHUNK];
    int   d[CHUNK];
#pragma unroll
    for (int k = 0; k < 8; ++k) {
        v[4*k+0]=va[k].x; v[4*k+1]=va[k].y; v[4*k+2]=va[k].z; v[4*k+3]=va[k].w;
        r[4*k+0]=ra[k].x; r[4*k+1]=ra[k].y; r[4*k+2]=ra[k].z; r[4*k+3]=ra[k].w;
        d[4*k+0]=da[k].x; d[4*k+1]=da[k].y; d[4*k+2]=da[k].z; d[4*k+3]=da[k].w;
    }

    // chunk boundary: values[col0+32] / done[col0+32] come from the next lane;
    // lane 63 (row end): nv = bootstrap next_value, done clamps to own d[31].
    const float v_nb = __shfl_down(v[0], 1);
    const int   d_nb = __shfl_down(d[0], 1);
    const float vnext  = (lane == 63) ? vboot : v_nb;
    const int   dnext  = (lane == 63) ? d[CHUNK-1] : d_nb;

    // ---- delta[t] and c[t] (dn[j] = done[t+1], nv[j] = values[t+1]) ----
    float delta[CHUNK], c[CHUNK];
#pragma unroll
    for (int j = 0; j < CHUNK; ++j) {
        const int   dn  = (j < CHUNK-1) ? d[j+1] : dnext;
        const float nv  = (j < CHUNK-1) ? v[j+1] : vnext;
        const float nnt = 1.0f - (float)dn;
        delta[j] = r[j] + GAMMA * nv * nnt - v[j];
        c[j]     = (GAMMA * LAM) * nnt;
    }

    // ---- per-thread affine composition over the chunk (backward) ----
    float a = 0.0f, m = 1.0f;
#pragma unroll
    for (int j = CHUNK - 1; j >= 0; --j) {
        a = delta[j] + c[j] * a;
        m = c[j] * m;
    }

    // ---- 64-lane inclusive SUFFIX scan of affine fns (self ∘ higher-lane) ----
    float sa = a, sm = m;
#pragma unroll
    for (int dd = 1; dd < 64; dd <<= 1) {
        float oa = __shfl_down(sa, dd);
        float om = __shfl_down(sm, dd);
        if (lane + dd < 64) { sa = sa + sm * oa; sm = sm * om; }
    }
    // exclusive-within-wave: gae entering this thread's chunk from the right
    float gin = __shfl_down(sa, 1);
    if (lane == 63) gin = 0.0f;

    // ---- replay: exact sequential recurrence over the chunk ----
#pragma unroll
    for (int j = CHUNK - 1; j >= 0; --j) {
        gin = delta[j] + c[j] * gin;
        delta[j] = gin;                          // delta[] now holds advantages
    }

    // ---- lane-contiguous-per-thread vectorized stores ----
    float4* a4 = reinterpret_cast<float4*>(adv_out + rowbase + col0);
    float4* t4 = reinterpret_cast<float4*>(ret_out + rowbase + col0);
#pragma unroll
    for (int k = 0; k < 8; ++k)
        a4[k] = make_float4(delta[4*k+0], delta[4*k+1], delta[4*k+2], delta[4*k+3]);
#pragma unroll
    for (int k = 0; k < 8; ++k)
        t4[k] = make_float4(delta[4*k+0]+v[4*k+0], delta[4*k+1]+v[4*k+1],
                            delta[4*k+2]+v[4*k+2], delta[4*k+3]+v[4*k+3]);
}

// Fallback for shapes where T != 64*CHUNK: one thread per row, sequential.
__global__ void gae_naive_kernel(
    const float* __restrict__ rewards,
    const float* __restrict__ values,
    const float* __restrict__ next_value,
    const int*   __restrict__ done,
    float* __restrict__ adv_out,
    float* __restrict__ ret_out,
    int B, int T)
{
    int row = blockIdx.x * blockDim.x + threadIdx.x;
    if (row >= B) return;
    long base = (long)row * T;
    float g = 0.0f;
    for (int t = T - 1; t >= 0; --t) {
        int dcol = (t + 1 < T) ? (t + 1) : (T - 1);
        float nnt = 1.0f - (float)done[base + dcol];
        float nv  = (t + 1 < T) ? values[base + t + 1] : next_value[row];
        float dl  = rewards[base + t] + GAMMA * nv * nnt - values[base + t];
        g = dl + (GAMMA * LAM) * nnt * g;
        adv_out[base + t] = g;
        ret_out[base + t] = g + values[base + t];
    }
}

extern "C" void kernel_launch(void* const* d_in, const int* in_sizes, int n_in,
                              void* d_out, int out_size, void* d_ws, size_t ws_size,
                              hipStream_t stream) {
    const float* rewards    = (const float*)d_in[0];
    const float* values     = (const float*)d_in[1];
    const float* next_value = (const float*)d_in[2];
    const int*   done       = (const int*)d_in[3];

    const int B = in_sizes[2];               // next_value is [B]
    const int T = in_sizes[0] / B;           // rewards is [B, T]

    float* adv = (float*)d_out;
    float* ret = adv + (long)B * T;

    if (T == 64 * CHUNK) {
        const int grid = (B + WPB - 1) / WPB;
        gae_wave_kernel<<<grid, BLOCK, 0, stream>>>(
            rewards, values, next_value, done, adv, ret, B, T);
    } else {
        gae_naive_kernel<<<(B + 255) / 256, 256, 0, stream>>>(
            rewards, values, next_value, done, adv, ret, B, T);
    }
}

// Round 5
// 148.718 us; speedup vs baseline: 1.0632x; 1.0632x over previous
//
#include <hip/hip_runtime.h>

#define GAMMA 0.99f
#define LAM   0.95f

constexpr int BLOCK  = 512;          // 8 waves
constexpr int CHUNK  = 4;            // timesteps per thread; requires T == BLOCK*CHUNK
constexpr int NWAVES = BLOCK / 64;
constexpr int GRID_TARGET = 1024;    // 4 blocks/CU on 256 CUs -> 32 waves/CU resident

typedef float f32x4 __attribute__((ext_vector_type(4)));

// Per-row register state (double-buffered across the row loop).
// All main loads are ONE lane-contiguous float4/int4 per array:
// thread tid covers [tid*4, tid*4+4) -> a wave's load = 1024B contiguous.
struct RowRegs {
    float4 ra, va;
    int4   da;
    float  bv;    // values[col0+CHUNK]            (lane 63 only)
    int    bd;    // done[min(col0+CHUNK, T-1)]    (lane 63 only)
    float  vboot; // next_value[row]               (tid == BLOCK-1 only)
};

__device__ __forceinline__ void load_row(
    const float* __restrict__ rewards, const float* __restrict__ values,
    const float* __restrict__ next_value, const int* __restrict__ done,
    int row, int T, int col0, int lane, int tid, RowRegs& R)
{
    const long rowbase = (long)row * T;
    R.ra = *reinterpret_cast<const float4*>(rewards + rowbase + col0);
    R.va = *reinterpret_cast<const float4*>(values  + rowbase + col0);
    R.da = *reinterpret_cast<const int4*>(done      + rowbase + col0);
    if (lane == 63) {
        const int bcol = (col0 + CHUNK < T) ? (col0 + CHUNK) : (T - 1);
        R.bv = values[rowbase + bcol];
        R.bd = done[rowbase + bcol];
    }
    if (tid == BLOCK - 1) R.vboot = next_value[row];
}

// One block per row-group (persistent over rows {bid + k*grid}). Backward
// linear recurrence g[t] = delta[t] + c[t]*g[t+1] via affine composition:
// per-thread 4-deep compose, 64-lane wave suffix-scan, 8-wave LDS combine.
// Outputs are written with NON-TEMPORAL stores: they are dead lines (never
// re-read), and regular stores were evicting the 96MB input set from L3
// every iteration (FETCH_SIZE pinned at ~49MB). Store layout is fully
// lane-contiguous (block covers the whole 8KB row) so every NT wave-store
// writes complete 64B lines -> no write amplification (unlike the R1 try).
__global__ __launch_bounds__(BLOCK, 8) void gae_scan_kernel(
    const float* __restrict__ rewards,
    const float* __restrict__ values,
    const float* __restrict__ next_value,
    const int*   __restrict__ done,
    float* __restrict__ adv_out,
    float* __restrict__ ret_out,
    int B, int T)
{
    const int tid  = threadIdx.x;
    const int lane = tid & 63;
    const int wave = tid >> 6;
    const int col0 = tid * CHUNK;

    __shared__ float lds_a[2][NWAVES];
    __shared__ float lds_m[2][NWAVES];

    RowRegs cur, nxt;
    load_row(rewards, values, next_value, done, blockIdx.x, T, col0, lane, tid, cur);

    int parity = 0;
    for (int row = blockIdx.x; row < B; row += gridDim.x) {
        // ---- prefetch next row while we compute this one ----
        const int nrow = row + gridDim.x;
        if (nrow < B)
            load_row(rewards, values, next_value, done, nrow, T, col0, lane, tid, nxt);

        const long rowbase = (long)row * T;

        // ---- unpack current row ----
        float v[CHUNK], r[CHUNK];
        v[0]=cur.va.x; v[1]=cur.va.y; v[2]=cur.va.z; v[3]=cur.va.w;
        r[0]=cur.ra.x; r[1]=cur.ra.y; r[2]=cur.ra.z; r[3]=cur.ra.w;

        // neighbor thread's first elements via intra-wave shuffle
        const float v_nb = __shfl_down(cur.va.x, 1);
        const int   d_nb = __shfl_down(cur.da.x, 1);
        float vnext  = (lane == 63) ? cur.bv : v_nb;          // values[col0+CHUNK]
        float dnextf = (float)((lane == 63) ? cur.bd : d_nb); // done[col0+CHUNK]
        if (tid == BLOCK - 1) vnext = cur.vboot;              // bootstrap at t=T-1

        // done[tcol+1] per owned tcol (in-register shift of the int4)
        float dn[CHUNK];
        dn[0]=(float)cur.da.y; dn[1]=(float)cur.da.z; dn[2]=(float)cur.da.w; dn[3]=dnextf;
        float nv[CHUNK];
        nv[0]=v[1]; nv[1]=v[2]; nv[2]=v[3]; nv[3]=vnext;

        // ---- delta[t] and c[t] ----
        float delta[CHUNK], c[CHUNK];
#pragma unroll
        for (int j = 0; j < CHUNK; ++j) {
            const float nnt = 1.0f - dn[j];
            delta[j] = r[j] + GAMMA * nv[j] * nnt - v[j];
            c[j]     = (GAMMA * LAM) * nnt;
        }

        // ---- per-thread affine composition over the chunk (backward) ----
        float a = 0.0f, m = 1.0f;
#pragma unroll
        for (int j = CHUNK - 1; j >= 0; --j) {
            a = delta[j] + c[j] * a;
            m = c[j] * m;
        }

        // ---- wave-level inclusive SUFFIX scan of affine fns ----
        float sa = a, sm = m;
#pragma unroll
        for (int d = 1; d < 64; d <<= 1) {
            float oa = __shfl_down(sa, d);
            float om = __shfl_down(sm, d);
            if (lane + d < 64) { sa = sa + sm * oa; sm = sm * om; }
        }
        float ea = __shfl_down(sa, 1);   // exclusive-within-wave
        float em = __shfl_down(sm, 1);
        if (lane == 63) { ea = 0.0f; em = 1.0f; }

        // ---- cross-wave composition via parity-buffered LDS ----
        if (lane == 0) { lds_a[parity][wave] = sa; lds_m[parity][wave] = sm; }
        __syncthreads();
        float g = 0.0f;
        for (int j = NWAVES - 1; j > wave; --j)
            g = lds_a[parity][j] + lds_m[parity][j] * g;
        float gin = ea + em * g;         // gae entering this thread's chunk

        // ---- replay: exact sequential recurrence over the chunk ----
#pragma unroll
        for (int j = CHUNK - 1; j >= 0; --j) {
            gin = delta[j] + c[j] * gin;
            delta[j] = gin;              // delta[] now holds advantages
        }

        // ---- lane-contiguous NON-TEMPORAL stores (full 64B lines/wave) ----
        f32x4* a4 = reinterpret_cast<f32x4*>(adv_out + rowbase + col0);
        f32x4* t4 = reinterpret_cast<f32x4*>(ret_out + rowbase + col0);
        f32x4 oa4 = { delta[0], delta[1], delta[2], delta[3] };
        f32x4 ot4 = { delta[0]+v[0], delta[1]+v[1], delta[2]+v[2], delta[3]+v[3] };
        __builtin_nontemporal_store(oa4, a4);
        __builtin_nontemporal_store(ot4, t4);

        parity ^= 1;
        cur = nxt;   // register move; dead after the last row
    }
}

// Fallback for shapes where T != BLOCK*CHUNK: one thread per row, sequential.
__global__ void gae_naive_kernel(
    const float* __restrict__ rewards,
    const float* __restrict__ values,
    const float* __restrict__ next_value,
    const int*   __restrict__ done,
    float* __restrict__ adv_out,
    float* __restrict__ ret_out,
    int B, int T)
{
    int row = blockIdx.x * blockDim.x + threadIdx.x;
    if (row >= B) return;
    long base = (long)row * T;
    float g = 0.0f;
    for (int t = T - 1; t >= 0; --t) {
        int dcol = (t + 1 < T) ? (t + 1) : (T - 1);
        float nnt = 1.0f - (float)done[base + dcol];
        float nv  = (t + 1 < T) ? values[base + t + 1] : next_value[row];
        float dl  = rewards[base + t] + GAMMA * nv * nnt - values[base + t];
        g = dl + (GAMMA * LAM) * nnt * g;
        adv_out[base + t] = g;
        ret_out[base + t] = g + values[base + t];
    }
}

extern "C" void kernel_launch(void* const* d_in, const int* in_sizes, int n_in,
                              void* d_out, int out_size, void* d_ws, size_t ws_size,
                              hipStream_t stream) {
    const float* rewards    = (const float*)d_in[0];
    const float* values     = (const float*)d_in[1];
    const float* next_value = (const float*)d_in[2];
    const int*   done       = (const int*)d_in[3];

    const int B = in_sizes[2];               // next_value is [B]
    const int T = in_sizes[0] / B;           // rewards is [B, T]

    float* adv = (float*)d_out;
    float* ret = adv + (long)B * T;

    if (T == BLOCK * CHUNK) {
        const int grid = (B < GRID_TARGET) ? B : GRID_TARGET;
        gae_scan_kernel<<<grid, BLOCK, 0, stream>>>(
            rewards, values, next_value, done, adv, ret, B, T);
    } else {
        gae_naive_kernel<<<(B + 255) / 256, 256, 0, stream>>>(
            rewards, values, next_value, done, adv, ret, B, T);
    }
}